// Round 2
// baseline (194.701 us; speedup 1.0000x reference)
//
#include <hip/hip_runtime.h>
#include <math.h>

// Problem constants (fixed by setup_inputs)
#define NP 8192      // pred vertices
#define NG 12000     // gt vertices
#define NFP 16384    // pred faces
#define NFG 24000    // gt faces
#define EPSF 1e-6f

// uniform grid for NN: 16^3 cells over [0,1]^3, ~3 gt / ~2 pred per cell
#define GR 16
#define NC (GR*GR*GR)        // 4096
#define HCELL 0.0625f        // 1/16, exact power of two
#define QL 16                // lanes cooperating per NN query

// query_face grid (1024-thread blocks):
//   blocks 0..6 : LDS-resident face accumulation (4 pred-range + 3 gt-range)
//   then 128 pred-query blocks (64 queries each), then 188 gt-query blocks
#define PR_LDSB 4
#define PR_RANGE 2048        // pred vertices per LDS block (56 KB LDS)
#define GT_LDSB 3
#define GT_RANGE 4000        // gt vertices per LDS block (48 KB LDS)
#define FACE_LDS_BLOCKS (PR_LDSB + GT_LDSB)            // 7
#define PQB 64               // queries per 1024-thread block
#define PRED_QB (NP / PQB)                             // 128
#define GT_QB ((NG + PQB - 1) / PQB)                   // 188 (last partial)
#define QF_BLOCKS (FACE_LDS_BLOCKS + PRED_QB + GT_QB)  // 323
#define FIN_BLOCKS (NP / 256)                          // 32

// ---- workspace layout (bytes) ----
static constexpr size_t OFF_STARTP = 0;        // (NC+1) u32 cell start (pred), [NC]=NP
static constexpr size_t OFF_STARTG = 16640;    // (NC+1) u32 cell start (gt),  [NC]=NG
static constexpr size_t OFF_SORTP  = 33280;    // 8192  float4 (x,y,z,idx-as-float-bits)
static constexpr size_t OFF_SORTG  = 164352;   // 12000 float4
static constexpr size_t OFF_GTN    = 356352;   // NG*3 f32 gt normals (plain-stored)
static constexpr size_t OFF_PNN    = 500352;   // NP*3 f32 pred normals
static constexpr size_t OFF_NSUM   = 598656;   // NP*3 f32 laplacian neighbor sum
static constexpr size_t OFF_DEG    = 696960;   // NP   f32 laplacian degree
static constexpr size_t OFF_NEAR   = 729728;   // NP   i32 nearest gt (original idx)
static constexpr size_t OFF_ACCUM  = 762496;   // 8 f32 global accumulators
static constexpr size_t OFF_DONE   = 762528;   // 1 u32 done-counter for finish kernel

__device__ __forceinline__ int cell_of(float x) {
    int c = (int)(x * (float)GR);
    return min(max(c, 0), GR - 1);
}

// One block builds one point set end-to-end: histogram -> shuffle scan ->
// write start[] -> scatter into cell-sorted order via LDS cursor table.
__device__ __forceinline__ void build_cells(const float* __restrict__ pts, int n,
                                            unsigned* __restrict__ start,
                                            float4* __restrict__ sorted,
                                            unsigned* h, unsigned* wsum) {
    int t = threadIdx.x;                 // 0..1023
    int lane = t & 63, wid = t >> 6;     // 16 waves
    for (int i = t; i < NC; i += 1024) h[i] = 0u;
    __syncthreads();
    for (int i = t; i < n; i += 1024) {
        int c = (cell_of(pts[3*i+2]) * GR + cell_of(pts[3*i+1])) * GR + cell_of(pts[3*i]);
        atomicAdd(&h[c], 1u);
    }
    __syncthreads();
    // each thread owns 4 cells; wave-shuffle inclusive scan of thread sums
    unsigned a0 = h[4*t], a1 = h[4*t+1], a2 = h[4*t+2], a3 = h[4*t+3];
    unsigned tsum = a0 + a1 + a2 + a3;
    unsigned x = tsum;
    #pragma unroll
    for (int off = 1; off < 64; off <<= 1) {
        unsigned y = __shfl_up(x, off, 64);
        if (lane >= off) x += y;
    }
    if (lane == 63) wsum[wid] = x;       // wave totals
    __syncthreads();
    if (t < 16) {                        // scan 16 wave totals inside wave 0
        unsigned w = wsum[t];
        #pragma unroll
        for (int off = 1; off < 16; off <<= 1) {
            unsigned y = __shfl_up(w, off, 64);
            if (t >= off) w += y;
        }
        wsum[t] = w;                     // inclusive
    }
    __syncthreads();
    unsigned base = (wid ? wsum[wid-1] : 0u) + (x - tsum);  // exclusive prefix
    unsigned e0 = base, e1 = base + a0, e2 = base + a0 + a1, e3 = base + a0 + a1 + a2;
    start[4*t] = e0; start[4*t+1] = e1; start[4*t+2] = e2; start[4*t+3] = e3;
    // reuse h as the scatter cursor
    h[4*t] = e0; h[4*t+1] = e1; h[4*t+2] = e2; h[4*t+3] = e3;
    __syncthreads();
    for (int i = t; i < n; i += 1024) {
        float px = pts[3*i], py = pts[3*i+1], pz = pts[3*i+2];
        int c = (cell_of(pz) * GR + cell_of(py)) * GR + cell_of(px);
        unsigned pos = atomicAdd(&h[c], 1u);
        sorted[pos] = make_float4(px, py, pz, __int_as_float(i));
    }
    if (t == 0) start[NC] = (unsigned)n;   // end sentinel
}

// Dispatch 1: block 0 = pred build, block 1 = gt build, block 2 = tiny zero.
// (gtn/pnn/nsum/deg no longer need zeroing: LDS face blocks fully overwrite.)
__global__ __launch_bounds__(1024) void build_kernel(const float* __restrict__ pred,
                                                     const float* __restrict__ gt,
                                                     unsigned* __restrict__ startP,
                                                     unsigned* __restrict__ startG,
                                                     float4* __restrict__ sortP,
                                                     float4* __restrict__ sortG,
                                                     float* __restrict__ accum,
                                                     unsigned* __restrict__ done) {
    __shared__ unsigned h[NC];
    __shared__ unsigned wsum[16];
    if (blockIdx.x == 0) {
        build_cells(pred, NP, startP, sortP, h, wsum);
    } else if (blockIdx.x == 1) {
        build_cells(gt, NG, startG, sortG, h, wsum);
    } else {
        if (threadIdx.x < 8) accum[threadIdx.x] = 0.0f;
        if (threadIdx.x == 8) *done = 0u;
    }
}

__device__ __forceinline__ float wave_sum(float x) {
    #pragma unroll
    for (int o = 32; o > 0; o >>= 1) x += __shfl_down(x, o, 64);
    return x;
}

__device__ __forceinline__ unsigned long long u64min(unsigned long long a,
                                                     unsigned long long b) {
    return a < b ? a : b;
}

__device__ __forceinline__ unsigned long long pack_key(float px, float py, float pz,
                                                       float4 q) {
    float ddx = px - q.x, ddy = py - q.y, ddz = pz - q.z;
    float d2 = fmaf(ddx, ddx, fmaf(ddy, ddy, ddz*ddz));
    return ((unsigned long long)__float_as_uint(d2) << 32) |
           (unsigned)__float_as_int(q.w);
}

// Group-parallel NN via expanding-box search over the cell-sorted array.
// Inner point scan unrolled x4: 4 independent float4 loads in flight per
// waitcnt instead of 1 (the dependent-load chain was the latency bottleneck).
__device__ __forceinline__ unsigned long long group_nn(int lane,
                                                       float px, float py, float pz,
                                                       const float4* __restrict__ S,
                                                       const unsigned* __restrict__ cstart) {
    int cx = cell_of(px), cy = cell_of(py), cz = cell_of(pz);
    unsigned long long best = 0xFFFFFFFFFFFFFFFFULL;
    for (int r = 1; ; ++r) {
        int w = 2 * r + 1;
        int nrows = w * w;
        int x0 = max(cx - r, 0), x1 = min(cx + r, GR - 1);
        unsigned long long lb = 0xFFFFFFFFFFFFFFFFULL;
        for (int k = lane; k < nrows; k += QL) {
            int z = cz + k / w - r, y = cy + k % w - r;
            if (z >= 0 && z < GR && y >= 0 && y < GR) {
                int rowbase = (z * GR + y) * GR;
                unsigned s0 = cstart[rowbase + x0];
                unsigned s1 = cstart[rowbase + x1 + 1];
                unsigned t = s0;
                for (; t + 4 <= s1; t += 4) {
                    float4 q0 = S[t], q1 = S[t+1], q2 = S[t+2], q3 = S[t+3];
                    unsigned long long k0 = pack_key(px, py, pz, q0);
                    unsigned long long k1 = pack_key(px, py, pz, q1);
                    unsigned long long k2 = pack_key(px, py, pz, q2);
                    unsigned long long k3 = pack_key(px, py, pz, q3);
                    lb = u64min(lb, u64min(u64min(k0, k1), u64min(k2, k3)));
                }
                for (; t < s1; ++t) {
                    lb = u64min(lb, pack_key(px, py, pz, S[t]));
                }
            }
        }
        best = u64min(best, lb);
        #pragma unroll
        for (int m = 1; m < QL; m <<= 1)
            best = u64min(best, (unsigned long long)__shfl_xor((long long)best, m, 64));
        bool covered = (cx - r <= 0) & (cx + r >= GR - 1) &
                       (cy - r <= 0) & (cy + r >= GR - 1) &
                       (cz - r <= 0) & (cz + r >= GR - 1);
        if (covered) break;
        float blo = 1.0e30f;
        if (cx - r > 0)      blo = fminf(blo, px - (float)(cx - r) * HCELL);
        if (cx + r < GR - 1) blo = fminf(blo, (float)(cx + r + 1) * HCELL - px);
        if (cy - r > 0)      blo = fminf(blo, py - (float)(cy - r) * HCELL);
        if (cy + r < GR - 1) blo = fminf(blo, (float)(cy + r + 1) * HCELL - py);
        if (cz - r > 0)      blo = fminf(blo, pz - (float)(cz - r) * HCELL);
        if (cz + r < GR - 1) blo = fminf(blo, (float)(cz + r + 1) * HCELL - pz);
        float bd2 = __uint_as_float((unsigned)(best >> 32));
        if (bd2 <= blo * blo) break;   // NaN (no point found) -> false -> expand
    }
    return best;
}

// Dispatch 2 (1024-thr blocks):
//   blocks 0..3   : pred-face accumulation, vertex range [b*2048,(b+1)*2048)
//                   pnn+nsum+deg LDS-resident (56 KB), plain-store out.
//   blocks 4..6   : gt-face accumulation,  vertex range [g*4000,(g+1)*4000)
//                   gtn LDS-resident (48 KB), plain-store out.
//   blocks 7..    : NN queries (64 per block). ZERO global float atomics on
//                   hot data -> no HBM write-through RMW storm.
__global__ __launch_bounds__(1024) void query_face_kernel(const float* __restrict__ pred,
                                                          const int* __restrict__ pf,
                                                          const float* __restrict__ gt,
                                                          const int* __restrict__ gf,
                                                          const float4* __restrict__ sortP,
                                                          const float4* __restrict__ sortG,
                                                          const unsigned* __restrict__ startP,
                                                          const unsigned* __restrict__ startG,
                                                          float* __restrict__ gtn,
                                                          float* __restrict__ pnn,
                                                          float* __restrict__ nsum,
                                                          float* __restrict__ deg,
                                                          int* __restrict__ nearestIdx,
                                                          float* __restrict__ accum) {
    __shared__ float lds_f[14336];   // 56 KB: face-accum arrays (union by block role)
    __shared__ float qsum;
    int b = blockIdx.x;
    int t = threadIdx.x;

    if (b < PR_LDSB) {
        // ---- pred-face block: lpnn[0..6144) lnsum[6144..12288) ldeg[12288..14336)
        int rb = b * PR_RANGE;
        for (int i = t; i < 14336; i += 1024) lds_f[i] = 0.0f;
        __syncthreads();
        for (int f = t; f < NFP; f += 1024) {
            int i0 = pf[3*f], i1 = pf[3*f+1], i2 = pf[3*f+2];
            float ax = pred[3*i0], ay = pred[3*i0+1], az = pred[3*i0+2];
            float bx = pred[3*i1], by = pred[3*i1+1], bz = pred[3*i1+2];
            float cx = pred[3*i2], cy = pred[3*i2+1], cz = pred[3*i2+2];
            float ux = bx-ax, uy = by-ay, uz = bz-az;
            float wx = cx-ax, wy = cy-ay, wz = cz-az;
            float nx = uy*wz - uz*wy, ny = uz*wx - ux*wz, nz = ux*wy - uy*wx;
            if ((unsigned)(i0 - rb) < PR_RANGE) {
                int l = i0 - rb;
                atomicAdd(&lds_f[3*l+0], nx); atomicAdd(&lds_f[3*l+1], ny); atomicAdd(&lds_f[3*l+2], nz);
                atomicAdd(&lds_f[6144+3*l+0], bx+cx); atomicAdd(&lds_f[6144+3*l+1], by+cy); atomicAdd(&lds_f[6144+3*l+2], bz+cz);
                atomicAdd(&lds_f[12288+l], 2.0f);
            }
            if ((unsigned)(i1 - rb) < PR_RANGE) {
                int l = i1 - rb;
                atomicAdd(&lds_f[3*l+0], nx); atomicAdd(&lds_f[3*l+1], ny); atomicAdd(&lds_f[3*l+2], nz);
                atomicAdd(&lds_f[6144+3*l+0], cx+ax); atomicAdd(&lds_f[6144+3*l+1], cy+ay); atomicAdd(&lds_f[6144+3*l+2], cz+az);
                atomicAdd(&lds_f[12288+l], 2.0f);
            }
            if ((unsigned)(i2 - rb) < PR_RANGE) {
                int l = i2 - rb;
                atomicAdd(&lds_f[3*l+0], nx); atomicAdd(&lds_f[3*l+1], ny); atomicAdd(&lds_f[3*l+2], nz);
                atomicAdd(&lds_f[6144+3*l+0], ax+bx); atomicAdd(&lds_f[6144+3*l+1], ay+by); atomicAdd(&lds_f[6144+3*l+2], az+bz);
                atomicAdd(&lds_f[12288+l], 2.0f);
            }
        }
        __syncthreads();
        for (int i = t; i < 3*PR_RANGE; i += 1024) {
            pnn[3*rb + i]  = lds_f[i];
            nsum[3*rb + i] = lds_f[6144 + i];
        }
        for (int i = t; i < PR_RANGE; i += 1024) deg[rb + i] = lds_f[12288 + i];
        return;
    }
    if (b < FACE_LDS_BLOCKS) {
        // ---- gt-face block: lgtn[0..12000)
        int rb = (b - PR_LDSB) * GT_RANGE;
        for (int i = t; i < 3*GT_RANGE; i += 1024) lds_f[i] = 0.0f;
        __syncthreads();
        for (int f = t; f < NFG; f += 1024) {
            int i0 = gf[3*f], i1 = gf[3*f+1], i2 = gf[3*f+2];
            float ax = gt[3*i0], ay = gt[3*i0+1], az = gt[3*i0+2];
            float bx = gt[3*i1], by = gt[3*i1+1], bz = gt[3*i1+2];
            float cx = gt[3*i2], cy = gt[3*i2+1], cz = gt[3*i2+2];
            float ux = bx-ax, uy = by-ay, uz = bz-az;
            float wx = cx-ax, wy = cy-ay, wz = cz-az;
            float nx = uy*wz - uz*wy, ny = uz*wx - ux*wz, nz = ux*wy - uy*wx;
            if ((unsigned)(i0 - rb) < GT_RANGE) {
                int l = i0 - rb;
                atomicAdd(&lds_f[3*l+0], nx); atomicAdd(&lds_f[3*l+1], ny); atomicAdd(&lds_f[3*l+2], nz);
            }
            if ((unsigned)(i1 - rb) < GT_RANGE) {
                int l = i1 - rb;
                atomicAdd(&lds_f[3*l+0], nx); atomicAdd(&lds_f[3*l+1], ny); atomicAdd(&lds_f[3*l+2], nz);
            }
            if ((unsigned)(i2 - rb) < GT_RANGE) {
                int l = i2 - rb;
                atomicAdd(&lds_f[3*l+0], nx); atomicAdd(&lds_f[3*l+1], ny); atomicAdd(&lds_f[3*l+2], nz);
            }
        }
        __syncthreads();
        for (int i = t; i < 3*GT_RANGE; i += 1024) gtn[3*rb + i] = lds_f[i];
        return;
    }

    // ---- query blocks ----
    if (t == 0) qsum = 0.0f;
    __syncthreads();
    int b2 = b - FACE_LDS_BLOCKS;
    int lane = t & (QL - 1);
    int group = t >> 4;                  // 0..63
    bool is_pred = (b2 < PRED_QB);
    float r0 = 0.0f;
    if (is_pred) {
        int qid = b2 * PQB + group;      // < 8192 exact
        float4 P = sortP[qid];
        unsigned long long key = group_nn(lane, P.x, P.y, P.z, sortG, startG);
        if (lane == 0) {
            int v = __float_as_int(P.w); // original pred index
            nearestIdx[v] = (int)(unsigned)(key & 0xffffffffu);
            r0 = __uint_as_float((unsigned)(key >> 32));
        }
    } else {
        int qid = (b2 - PRED_QB) * PQB + group;
        if (qid < NG) {                  // group-uniform guard (last block partial)
            float4 Q = sortG[qid];
            unsigned long long key = group_nn(lane, Q.x, Q.y, Q.z, sortP, startP);
            if (lane == 0) r0 = __uint_as_float((unsigned)(key >> 32));
        }
    }
    r0 = wave_sum(r0);
    if ((t & 63) == 0) atomicAdd(&qsum, r0);   // 16 wave leaders -> LDS
    __syncthreads();
    if (t == 0) atomicAdd(&accum[is_pred ? 0 : 6], qsum);
}

// Dispatch 3: fully-parallel per-vertex epilogue; last block (done-counter)
// computes the final scalar.
__global__ __launch_bounds__(256) void finish_kernel(const float* __restrict__ pred,
                                                     const float* __restrict__ relpos,
                                                     const int* __restrict__ label,
                                                     const float* __restrict__ pnn,
                                                     const float* __restrict__ gtn,
                                                     const float* __restrict__ nsum,
                                                     const float* __restrict__ deg,
                                                     const int* __restrict__ nearestIdx,
                                                     float* __restrict__ accum,
                                                     unsigned* __restrict__ done,
                                                     float* __restrict__ out) {
    int v = blockIdx.x * 256 + threadIdx.x;     // < 8192 exact
    float px = pred[3*v], py = pred[3*v+1], pz = pred[3*v+2];
    int nearest = nearestIdx[v];

    // normal consistency (normalize both accumulators on the fly)
    float ax = pnn[3*v], ay = pnn[3*v+1], az = pnn[3*v+2];
    float an = fmaxf(sqrtf(ax*ax + ay*ay + az*az), EPSF);
    float gx = gtn[3*nearest], gy = gtn[3*nearest+1], gz = gtn[3*nearest+2];
    float gn = fmaxf(sqrtf(gx*gx + gy*gy + gz*gz), EPSF);
    float nx = ax/an - gx/gn, ny = ay/an - gy/gn, nz = az/an - gz/gn;
    float sse = nx*nx + ny*ny + nz*nz;

    // laplacian
    float d = fmaxf(deg[v], 1.0f);
    float lx = nsum[3*v]/d - px, ly = nsum[3*v+1]/d - py, lz = nsum[3*v+2]/d - pz;
    float lapn = sqrtf(lx*lx + ly*ly + lz*lz);

    // grid-sample target (nearest, align_corners=True, zeros padding)
    int ix = (int)rintf(px * 95.0f), iy = (int)rintf(py * 95.0f), iz = (int)rintf(pz * 95.0f);
    bool inb = (ix >= 0) & (ix < 96) & (iy >= 0) & (iy < 96) & (iz >= 0) & (iz < 96);
    int ixc = min(max(ix, 0), 95), iyc = min(max(iy, 0), 95), izc = min(max(iz, 0), 95);
    bool pos = inb && (label[(izc*96 + iyc)*96 + ixc] == 1);

    float p = fminf(fmaxf(relpos[v], EPSF), 1.0f - EPSF);
    float om = 1.0f - p;
    float pcnt = 0.0f, sx = 0.0f, sy = 0.0f;
    if (pos) { pcnt = 1.0f; sx = om*om*logf(p); }
    else     { sy = p*p*logf(om); }

    float r1 = wave_sum(sse), r2 = wave_sum(lapn), r3 = wave_sum(pcnt);
    float r4 = wave_sum(sx),  r5 = wave_sum(sy);
    __shared__ float bsum[5];
    __shared__ bool isLast;
    if (threadIdx.x < 5) bsum[threadIdx.x] = 0.0f;
    __syncthreads();
    if ((threadIdx.x & 63) == 0) {
        atomicAdd(&bsum[0], r1); atomicAdd(&bsum[1], r2); atomicAdd(&bsum[2], r3);
        atomicAdd(&bsum[3], r4); atomicAdd(&bsum[4], r5);
    }
    __syncthreads();
    if (threadIdx.x == 0) {
        atomicAdd(&accum[1], bsum[0]); atomicAdd(&accum[2], bsum[1]);
        atomicAdd(&accum[3], bsum[2]); atomicAdd(&accum[4], bsum[3]);
        atomicAdd(&accum[5], bsum[4]);
        __threadfence();                         // publish before done-count
        unsigned prev = atomicAdd(done, 1u);
        isLast = (prev == FIN_BLOCKS - 1);
    }
    __syncthreads();
    if (isLast && threadIdx.x == 0) {
        __threadfence();
        float sum_row = __hip_atomic_load(&accum[0], __ATOMIC_RELAXED, __HIP_MEMORY_SCOPE_AGENT);
        float sse_t   = __hip_atomic_load(&accum[1], __ATOMIC_RELAXED, __HIP_MEMORY_SCOPE_AGENT);
        float lap_t   = __hip_atomic_load(&accum[2], __ATOMIC_RELAXED, __HIP_MEMORY_SCOPE_AGENT);
        float pc      = __hip_atomic_load(&accum[3], __ATOMIC_RELAXED, __HIP_MEMORY_SCOPE_AGENT);
        float SX      = __hip_atomic_load(&accum[4], __ATOMIC_RELAXED, __HIP_MEMORY_SCOPE_AGENT);
        float SY      = __hip_atomic_load(&accum[5], __ATOMIC_RELAXED, __HIP_MEMORY_SCOPE_AGENT);
        float sum_col = __hip_atomic_load(&accum[6], __ATOMIC_RELAXED, __HIP_MEMORY_SCOPE_AGENT);
        float tot = (float)NP;
        float alpha = (tot - pc) / (tot + EPSF);
        float spatial = (-alpha * SX - (1.0f - alpha) * SY) / (tot + EPSF);
        float distance = sum_row / (float)NP + sum_col / (float)NG;
        float normal = sse_t / (float)(NP * 3);
        float lapm = lap_t / (float)NP;
        out[0] = spatial + 1.0f * distance + 0.01f * normal + 0.1f * lapm;
    }
}

extern "C" void kernel_launch(void* const* d_in, const int* in_sizes, int n_in,
                              void* d_out, int out_size, void* d_ws, size_t ws_size,
                              hipStream_t stream) {
    const float* pred   = (const float*)d_in[0];   // [8192,3]
    const float* relpos = (const float*)d_in[1];   // [8192]
    const float* gt     = (const float*)d_in[2];   // [12000,3]
    const int*   pfaces = (const int*)d_in[3];     // [16384,3]
    const int*   gfaces = (const int*)d_in[4];     // [24000,3]
    const int*   label  = (const int*)d_in[5];     // [1,1,96,96,96]
    float* out = (float*)d_out;

    char* ws = (char*)d_ws;
    unsigned* startP  = (unsigned*)(ws + OFF_STARTP);
    unsigned* startG  = (unsigned*)(ws + OFF_STARTG);
    float4*   sortP   = (float4*)(ws + OFF_SORTP);
    float4*   sortG   = (float4*)(ws + OFF_SORTG);
    float*    gtn     = (float*)(ws + OFF_GTN);
    float*    pnn     = (float*)(ws + OFF_PNN);
    float*    nsum    = (float*)(ws + OFF_NSUM);
    float*    deg     = (float*)(ws + OFF_DEG);
    int*      nearest = (int*)(ws + OFF_NEAR);
    float*    accum   = (float*)(ws + OFF_ACCUM);
    unsigned* done    = (unsigned*)(ws + OFF_DONE);

    // d1: hist+scan+scatter (blocks 0,1) + tiny accumulator zero (block 2)
    hipLaunchKernelGGL(build_kernel, dim3(3), dim3(1024), 0, stream,
                       pred, gt, startP, startG, sortP, sortG, accum, done);
    // d2: LDS face accumulation (7 blocks, first) || grid-NN queries
    hipLaunchKernelGGL(query_face_kernel, dim3(QF_BLOCKS), dim3(1024), 0, stream,
                       pred, pfaces, gt, gfaces, sortP, sortG, startP, startG,
                       gtn, pnn, nsum, deg, nearest, accum);
    // d3: parallel per-vertex epilogue + last-block final combine
    hipLaunchKernelGGL(finish_kernel, dim3(FIN_BLOCKS), dim3(256), 0, stream,
                       pred, relpos, label, pnn, gtn, nsum, deg, nearest,
                       accum, done, out);
}